// Round 5
// baseline (590.964 us; speedup 1.0000x reference)
//
#include <hip/hip_runtime.h>
#include <cstdint>
#include <cstddef>

constexpr int T_ = 128;
constexpr int S_ = 512;
constexpr int B_ = 256;
constexpr int START_ = T_ - 3;  // 125
constexpr int STOP_  = T_ - 2;  // 126

// Barrier draining only LDS (lgkmcnt), not vmcnt: global bp-stores and
// e-prefetch loads legally stay in flight across it (thread-private data).
__device__ __forceinline__ void lds_barrier() {
  asm volatile("s_waitcnt lgkmcnt(0)\n\ts_barrier" ::: "memory");
}

// max/min reduce over the 8 ig-lanes (lane bits [0,3)) in pure DPP:
// quad xor1 (0xB1), quad xor2 (0x4E), half-row mirror (0x141; valid as xor4
// because the value is quad-uniform after the first two stages).
__device__ __forceinline__ float ig_rmax(float m) {
  int x = __builtin_amdgcn_mov_dpp(__float_as_int(m), 0xB1, 0xF, 0xF, true);
  m = fmaxf(m, __int_as_float(x));
  x = __builtin_amdgcn_mov_dpp(__float_as_int(m), 0x4E, 0xF, 0xF, true);
  m = fmaxf(m, __int_as_float(x));
  x = __builtin_amdgcn_mov_dpp(__float_as_int(m), 0x141, 0xF, 0xF, true);
  m = fmaxf(m, __int_as_float(x));
  return m;
}
__device__ __forceinline__ int ig_rmin(int m) {
  int x = __builtin_amdgcn_mov_dpp(m, 0xB1, 0xF, 0xF, true);
  m = min(m, x);
  x = __builtin_amdgcn_mov_dpp(m, 0x4E, 0xF, 0xF, true);
  m = min(m, x);
  x = __builtin_amdgcn_mov_dpp(m, 0x141, 0xF, 0xF, true);
  m = min(m, x);
  return m;
}

// ---------------------------------------------------------------------------
// Forward: Viterbi recursion with value AND backpointer (first-occurrence
// argmax), bit-exact vs reference:
//   d_i = fl(fl(part_i + trans[i,j]) + e_j); np_j = max_i d_i
//   (== fl(max_i fl(p+t) + e) by monotonicity, so values match reference);
//   bp_j = first i achieving max (ties-to-left tournament + min-key reduce
//   over global index 16*ig+local — exact jnp.argmax semantics).
// Thread (ig, jg): i in [16ig,16ig+16) x j in [4jg,4jg+4).
// part in padded LDS (R4 scheme, measured 0 conflicts); trans tile in regs;
// emissions in an 8-row A/B register pipeline (4-8 steps of slack, covers
// L3/HBM latency that the old 1-deep prefetch exposed).
// bp row for step t is stored at row t-1 of (B,S,T) u8 (matches reference
// back_points indexing); part row at t==lp captured to lastpart (B,T).
// ---------------------------------------------------------------------------
__global__ __launch_bounds__(256) void viterbi_forward(
    const float* __restrict__ feats,   // (B,S,T)
    const float* __restrict__ trans,   // (T,T)
    const void*  __restrict__ mask,    // (B,S)
    unsigned int* __restrict__ bp4,    // (B,S,T) u8 viewed as u32
    float* __restrict__ lastpart)      // (B,T)
{
  const int b    = blockIdx.x;
  const int tid  = threadIdx.x;
  const int lane = tid & 63;
  const int w    = tid >> 6;
  const int ig   = lane & 7;
  const int jl   = lane >> 3;
  const int jg   = w * 8 + jl;         // 0..31
  const int j0   = jg * 4;
  const int ig16 = ig * 16;

  __shared__ alignas(16) float part[2][160];  // value i at offset i + 4*(i>>4)
  __shared__ int lensh[4];

  // trans tile, split per j-component: tcc[c][i] = trans[16ig+i][j0+c]
  float tcc[4][16];
  #pragma unroll
  for (int ii = 0; ii < 16; ++ii) {
    float4 v = *(const float4*)&trans[(ig16 + ii) * T_ + j0];
    tcc[0][ii] = v.x; tcc[1][ii] = v.y; tcc[2][ii] = v.z; tcc[3][ii] = v.w;
  }

  // sequence length (mask dtype: uint8 / float32 / int32)
  int cnt = 0;
  {
    const int w0 = *(const int*)mask;  // element (0,0) is always true
    if (w0 == 0x01010101) {
      const unsigned char* m = (const unsigned char*)mask + (size_t)b * S_;
      cnt = (m[tid] != 0) + (m[tid + 256] != 0);
    } else if (w0 == 0x3F800000) {
      const float* m = (const float*)mask + (size_t)b * S_;
      cnt = (m[tid] != 0.0f) + (m[tid + 256] != 0.0f);
    } else {
      const int* m = (const int*)mask + (size_t)b * S_;
      cnt = (m[tid] != 0) + (m[tid + 256] != 0);
    }
    #pragma unroll
    for (int o = 32; o > 0; o >>= 1) cnt += __shfl_xor(cnt, o);
    if (lane == 0) lensh[w] = cnt;
  }

  const float* fb   = feats + (size_t)b * S_ * T_;
  const int    woff = j0 + 4 * (jg >> 2);

  // t = 0
  float4 e0v = *(const float4*)&fb[j0];
  float4 tsv = *(const float4*)&trans[START_ * T_ + j0];
  float4 p0  = {e0v.x + tsv.x, e0v.y + tsv.y, e0v.z + tsv.z, e0v.w + tsv.w};
  if (ig == 0) *(float4*)&part[0][woff] = p0;
  __syncthreads();
  const int lp = lensh[0] + lensh[1] + lensh[2] + lensh[3] - 1;  // >= 255

  auto stepf = [&](int t, float4 e4) {
    const float4* p4 = (const float4*)part[(t - 1) & 1];
    float pp[16];
    #pragma unroll
    for (int q = 0; q < 4; ++q) {
      float4 v = p4[5 * ig + q];
      pp[4*q] = v.x; pp[4*q+1] = v.y; pp[4*q+2] = v.z; pp[4*q+3] = v.w;
    }
    const float ev[4] = {e4.x, e4.y, e4.z, e4.w};
    float np[4]; int bpk[4];
    #pragma unroll
    for (int c = 0; c < 4; ++c) {
      // fused d-compute + tournament level 1 (ties-to-left everywhere)
      float v8[8]; int i8[8];
      #pragma unroll
      for (int a = 0; a < 8; ++a) {
        float da = (pp[2*a]     + tcc[c][2*a])     + ev[c];
        float db = (pp[2*a + 1] + tcc[c][2*a + 1]) + ev[c];
        bool s = da >= db;
        v8[a] = s ? da : db; i8[a] = s ? (2*a) : (2*a + 1);
      }
      float v4[4]; int i4[4];
      #pragma unroll
      for (int a = 0; a < 4; ++a) {
        bool s = v8[2*a] >= v8[2*a + 1];
        v4[a] = s ? v8[2*a] : v8[2*a + 1]; i4[a] = s ? i8[2*a] : i8[2*a + 1];
      }
      float v2[2]; int i2[2];
      #pragma unroll
      for (int a = 0; a < 2; ++a) {
        bool s = v2[0] >= 0;  // placeholder overwritten below
        (void)s;
        bool ss = v4[2*a] >= v4[2*a + 1];
        v2[a] = ss ? v4[2*a] : v4[2*a + 1]; i2[a] = ss ? i4[2*a] : i4[2*a + 1];
      }
      bool s0 = v2[0] >= v2[1];
      float cv = s0 ? v2[0] : v2[1];
      int   ci = s0 ? i2[0] : i2[1];
      float M = ig_rmax(cv);
      int key = (cv == M) ? (ig16 + ci) : 255;
      key = ig_rmin(key);                 // first-occurrence global argmax
      np[c] = M; bpk[c] = key;
    }
    float4 np4 = {np[0], np[1], np[2], np[3]};
    if (ig == 0) *(float4*)&part[t & 1][woff] = np4;
    lds_barrier();
    if (ig == 0) {                        // off critical path
      unsigned pk = (unsigned)bpk[0] | ((unsigned)bpk[1] << 8) |
                    ((unsigned)bpk[2] << 16) | ((unsigned)bpk[3] << 24);
      bp4[(size_t)(b * S_ + (t - 1)) * 32 + jg] = pk;
      if (t == lp) *(float4*)&lastpart[b * T_ + j0] = np4;
    }
  };

  // emission pipeline: 8 rows in flight (A/B groups of 4)
  float4 EA[4], EB[4];
  #pragma unroll
  for (int u = 0; u < 4; ++u)
    EA[u] = *(const float4*)&fb[(size_t)(1 + u) * T_ + j0];

  for (int t0 = 1; t0 < S_; t0 += 8) {
    #pragma unroll
    for (int u = 0; u < 4; ++u) {
      int tr = t0 + 4 + u; tr = tr > S_ - 1 ? S_ - 1 : tr;
      EB[u] = *(const float4*)&fb[(size_t)tr * T_ + j0];
    }
    #pragma unroll
    for (int u = 0; u < 4; ++u) { int t = t0 + u; if (t < S_) stepf(t, EA[u]); }
    #pragma unroll
    for (int u = 0; u < 4; ++u) {
      int tr = t0 + 8 + u; tr = tr > S_ - 1 ? S_ - 1 : tr;
      EA[u] = *(const float4*)&fb[(size_t)tr * T_ + j0];
    }
    #pragma unroll
    for (int u = 0; u < 4; ++u) { int t = t0 + 4 + u; if (t < S_) stepf(t, EB[u]); }
  }
}

// ---------------------------------------------------------------------------
// Trace: one wave per b. Stage the 64 KB bp[b] slab into LDS (bulk,
// coalesced, 8-deep pipelined), compute the final pointer from lastpart +
// trans[:,STOP] (first-occurrence argmax, bit-exact), zero-fill the masked
// tail, then chase pointers entirely in LDS: ~130 cyc per ds_read_u8 step.
// ---------------------------------------------------------------------------
__global__ __launch_bounds__(64) void viterbi_trace(
    const float* __restrict__ trans,          // (T,T)
    const void*  __restrict__ mask,           // (B,S)
    const unsigned char* __restrict__ bp,     // (B,S,T) u8
    const float* __restrict__ lastpart,       // (B,T)
    int* __restrict__ out)                    // (B,S)
{
  const int b    = blockIdx.x;
  const int lane = threadIdx.x;

  __shared__ unsigned char bplds[S_ * T_];    // 64 KB

  // stage bp[b] -> LDS (4096 uint4, 64/lane, 8-deep)
  {
    const uint4* g = (const uint4*)(bp + (size_t)b * S_ * T_);
    uint4* l = (uint4*)bplds;
    #pragma unroll
    for (int r = 0; r < 64; r += 8) {
      uint4 v[8];
      #pragma unroll
      for (int q = 0; q < 8; ++q) v[q] = g[(r + q) * 64 + lane];
      #pragma unroll
      for (int q = 0; q < 8; ++q) l[(r + q) * 64 + lane] = v[q];
    }
  }

  // sequence length
  int len = 0;
  {
    const int w0 = *(const int*)mask;
    if (w0 == 0x01010101) {
      const unsigned char* m = (const unsigned char*)mask + (size_t)b * S_;
      for (int s = lane; s < S_; s += 64) len += (m[s] != 0);
    } else if (w0 == 0x3F800000) {
      const float* m = (const float*)mask + (size_t)b * S_;
      for (int s = lane; s < S_; s += 64) len += (m[s] != 0.0f);
    } else {
      const int* m = (const int*)mask + (size_t)b * S_;
      for (int s = lane; s < S_; s += 64) len += (m[s] != 0);
    }
    #pragma unroll
    for (int o = 32; o > 0; o >>= 1) len += __shfl_xor(len, o);
  }
  const int lp = len - 1;

  // final pointer: first argmax_i( lastpart[i] + trans[i][STOP] )
  const float2 L = *(const float2*)(lastpart + b * T_ + 2 * lane);
  float tr0 = trans[(2 * lane) * T_ + STOP_];
  float tr1 = trans[(2 * lane + 1) * T_ + STOP_];
  float v0 = L.x + tr0, v1 = L.y + tr1;
  float mx = fmaxf(v0, v1);
  #pragma unroll
  for (int o = 32; o > 0; o >>= 1) mx = fmaxf(mx, __shfl_xor(mx, o));
  unsigned long long g0 = __ballot(v0 == mx);
  unsigned long long g1 = __ballot(v1 == mx);
  int p0 = g0 ? 2 * (__ffsll(g0) - 1)     : (1 << 30);
  int p1 = g1 ? 2 * (__ffsll(g1) - 1) + 1 : (1 << 30);
  const int pointer = min(p0, p1);

  // masked tail: out[k]=0 for lp<k<=S-2; out[S-1]=pointer; out[lp]=pointer
  for (int k = lp + 1 + lane; k <= S_ - 2; k += 64) out[b * S_ + k] = 0;
  if (lane == 0) {
    out[b * S_ + (S_ - 1)] = pointer;
    if (lp < S_ - 1) out[b * S_ + lp] = pointer;
  }

  __syncthreads();  // LDS staging visible (single wave: trivially cheap)

  // chase: bp row k holds step k+1's argmax (reference back_points[k])
  if (lane == 0) {
    int ptr = pointer;
    for (int k = lp - 1; k >= 0; --k) {
      ptr = bplds[k * T_ + ptr];
      out[b * S_ + k] = ptr;
    }
  }
}

extern "C" void kernel_launch(void* const* d_in, const int* in_sizes, int n_in,
                              void* d_out, int out_size, void* d_ws, size_t ws_size,
                              hipStream_t stream) {
  const float* feats = (const float*)d_in[0];   // (B,S,T) fp32
  const void*  mask  = d_in[1];                 // (B,S) bool-ish
  const float* trans = (const float*)d_in[2];   // (T,T) fp32
  int* out = (int*)d_out;                       // (B,S) int32

  unsigned char* bp = (unsigned char*)d_ws;                       // 16 MiB
  float* lastpart = (float*)((char*)d_ws + (size_t)B_ * S_ * T_); // 128 KiB

  viterbi_forward<<<dim3(B_), dim3(256), 0, stream>>>(
      feats, trans, mask, (unsigned int*)bp, lastpart);
  viterbi_trace<<<dim3(B_), dim3(64), 0, stream>>>(
      trans, mask, bp, lastpart, out);
}

// Round 6
// 455.302 us; speedup vs baseline: 1.2980x; 1.2980x over previous
//
#include <hip/hip_runtime.h>
#include <cstdint>
#include <cstddef>

constexpr int T_ = 128;
constexpr int S_ = 512;
constexpr int B_ = 256;
constexpr int START_ = T_ - 3;  // 125
constexpr int STOP_  = T_ - 2;  // 126
constexpr float NEGINF_ = -3.402823466e38f;

// Barrier that only drains LDS (lgkmcnt), NOT vmcnt: global ph-stores and
// e-prefetch loads legally stay in flight across it (thread-private data).
__device__ __forceinline__ void lds_barrier() {
  asm volatile("s_waitcnt lgkmcnt(0)\n\ts_barrier" ::: "memory");
}

// readlane: wave-uniform lane index (SGPR) -> ~VALU-speed broadcast,
// vs __shfl which lowers to ds_bpermute (~LDS latency).
__device__ __forceinline__ float readlane_f(float v, int sl) {
  return __int_as_float(__builtin_amdgcn_readlane(__float_as_int(v), sl));
}

// max-reduce over the 8 ig-lanes (lane bits [0,3)) entirely in DPP:
// quad xor1 (0xB1), quad xor2 (0x4E), half-row mirror (0x141 == lane^7,
// valid because the value is quad-uniform after the first two stages).
__device__ __forceinline__ float ig_reduce_max(float m) {
  int x = __builtin_amdgcn_mov_dpp(__float_as_int(m), 0xB1, 0xF, 0xF, true);
  m = fmaxf(m, __int_as_float(x));
  x = __builtin_amdgcn_mov_dpp(__float_as_int(m), 0x4E, 0xF, 0xF, true);
  m = fmaxf(m, __int_as_float(x));
  x = __builtin_amdgcn_mov_dpp(__float_as_int(m), 0x141, 0xF, 0xF, true);
  m = fmaxf(m, __int_as_float(x));
  return m;
}

// ---------------------------------------------------------------------------
// Forward: value-only Viterbi recursion, stores part_hist (S,B,T) fp32.
// IDENTICAL to round-4 except __launch_bounds__(256, 1): rounds 1-5 all had
// VGPR_Count 48-76 (< the 64-reg trans tile alone!), i.e. the compiler was
// re-loading `trans` from L2 EVERY STEP (loop-invariant load sinking under
// the default-occupancy register budget). That L2-latency reload chain is
// the ~1400 cyc/step invariant. (256,1) grants ~512 VGPRs/thread at the
// occupancy we already have (grid 256 = 1 block/CU).
// Bit-exact vs reference: max exactly associative, fl monotone =>
// max_i fl(fl(p+tr)+e) == fl(max_i fl(p+tr) + e).
// ---------------------------------------------------------------------------
__global__ __launch_bounds__(256, 1) void viterbi_forward(
    const float* __restrict__ feats,   // (B,S,T)
    const float* __restrict__ trans,   // (T,T)
    float* __restrict__ ph)            // (S,B,T) workspace
{
  const int tid  = threadIdx.x;
  const int lane = tid & 63;
  const int w    = tid >> 6;           // wave 0..3
  const int ig   = lane & 7;           // i-chunk
  const int jl   = lane >> 3;          // 0..7
  const int jg   = w * 8 + jl;         // 0..31
  const int j0   = jg * 4;
  const int b    = blockIdx.x;

  // padded part: value i lives at float offset i + 4*(i>>4); 160 floats/buf
  __shared__ alignas(16) float part[2][160];

  // trans tile: rows 16ig..16ig+15, cols j0..j0+3 (float4 per row)
  float4 tc[16];
  #pragma unroll
  for (int ii = 0; ii < 16; ++ii)
    tc[ii] = *(const float4*)&trans[(16 * ig + ii) * T_ + j0];

  const float* fb = feats + (size_t)b * S_ * T_;
  const int woff = j0 + 4 * (jg >> 2);   // padded write offset for j-quad

  // t = 0: part0 = emit[0] + trans[START,:]
  float4 e0 = *(const float4*)&fb[j0];
  float4 ts = *(const float4*)&trans[START_ * T_ + j0];
  float4 p0 = make_float4(e0.x + ts.x, e0.y + ts.y, e0.z + ts.z, e0.w + ts.w);
  if (ig == 0) {
    *(float4*)&part[0][woff] = p0;
    *(float4*)&ph[(size_t)b * T_ + j0] = p0;
  }
  float4 e_next = *(const float4*)&fb[T_ + j0];
  __syncthreads();

  for (int t = 1; t < S_; ++t) {
    float4 e_cur = e_next;
    if (t + 1 < S_) e_next = *(const float4*)&fb[(size_t)(t + 1) * T_ + j0];

    const float4* p4 = (const float4*)part[(t - 1) & 1];
    float4 p[4];
    #pragma unroll
    for (int q = 0; q < 4; ++q) p[q] = p4[5 * ig + q];

    float m0 = NEGINF_, m1 = NEGINF_, m2 = NEGINF_, m3 = NEGINF_;
    #pragma unroll
    for (int q = 0; q < 4; ++q) {
      float4 pv = p[q];
      float4 t0 = tc[4 * q + 0], t1 = tc[4 * q + 1];
      float4 t2 = tc[4 * q + 2], t3 = tc[4 * q + 3];
      m0 = fmaxf(m0, fmaxf(fmaxf(pv.x + t0.x, pv.y + t1.x),
                           fmaxf(pv.z + t2.x, pv.w + t3.x)));
      m1 = fmaxf(m1, fmaxf(fmaxf(pv.x + t0.y, pv.y + t1.y),
                           fmaxf(pv.z + t2.y, pv.w + t3.y)));
      m2 = fmaxf(m2, fmaxf(fmaxf(pv.x + t0.z, pv.y + t1.z),
                           fmaxf(pv.z + t2.z, pv.w + t3.z)));
      m3 = fmaxf(m3, fmaxf(fmaxf(pv.x + t0.w, pv.y + t1.w),
                           fmaxf(pv.z + t2.w, pv.w + t3.w)));
    }
    float4 np4 = make_float4(ig_reduce_max(m0) + e_cur.x,
                             ig_reduce_max(m1) + e_cur.y,
                             ig_reduce_max(m2) + e_cur.z,
                             ig_reduce_max(m3) + e_cur.w);
    if (ig == 0) *(float4*)&part[t & 1][woff] = np4;
    lds_barrier();
    if (ig == 0)
      *(float4*)&ph[((size_t)t * B_ + b) * T_ + j0] = np4;  // off critical path
  }
}

// ---------------------------------------------------------------------------
// Trace: one wave (64 lanes) per b, grid 256. IDENTICAL to round-4 except
// __launch_bounds__(64, 1): the default budget (~64 VGPRs for 8 waves/SIMD)
// could not hold the 64-register A/B prefetch pipeline either — same
// load-sinking failure; (64,1) lets the 8-deep double-buffer actually live
// in registers. Bit-exact first-occurrence argmax vs reference.
// ---------------------------------------------------------------------------
constexpr int CH_ = 8;   // chunk size (steps per buffer)
constexpr int TS_ = 130; // transT row stride (even: float2-aligned, 2-way ok)

__global__ __launch_bounds__(64, 1) void viterbi_trace(
    const float* __restrict__ feats,   // (B,S,T)
    const void*  __restrict__ mask,    // (B,S) dtype detected at runtime
    const float* __restrict__ trans,   // (T,T)
    const float* __restrict__ ph,      // (S,B,T)
    int* __restrict__ out)             // (B,S) int32
{
  const int b    = blockIdx.x;
  const int lane = threadIdx.x;

  __shared__ alignas(16) float transT[T_ * TS_];  // transT[j*TS+i] = trans[i][j]
  #pragma unroll 4
  for (int g = lane; g < T_ * T_; g += 64) {
    int i = g >> 7, jj = g & (T_ - 1);
    transT[jj * TS_ + i] = trans[g];
  }
  __syncthreads();

  // ---- sequence length (mask dtype: uint8 / float32 / int32) ----
  int len = 0;
  {
    const int w0 = *(const int*)mask;  // element (0,0) is always true
    if (w0 == 0x01010101) {
      const unsigned char* m = (const unsigned char*)mask + (size_t)b * S_;
      for (int s = lane; s < S_; s += 64) len += (m[s] != 0);
    } else if (w0 == 0x3F800000) {
      const float* m = (const float*)mask + (size_t)b * S_;
      for (int s = lane; s < S_; s += 64) len += (m[s] != 0.0f);
    } else {
      const int* m = (const int*)mask + (size_t)b * S_;
      for (int s = lane; s < S_; s += 64) len += (m[s] != 0);
    }
    #pragma unroll
    for (int o = 32; o > 0; o >>= 1) len += __shfl_xor(len, o);
  }
  const int lp = len - 1;              // last valid position (>= S/2-1)

  // ---- final pointer: first argmax_i(ph_lp[i] + trans[i][STOP]) ----
  const float2 L = *(const float2*)(ph + ((size_t)lp * B_ + b) * T_ + 2 * lane);
  float v0 = L.x + transT[STOP_ * TS_ + 2 * lane];
  float v1 = L.y + transT[STOP_ * TS_ + 2 * lane + 1];
  float mx = fmaxf(v0, v1);
  #pragma unroll
  for (int o = 32; o > 0; o >>= 1) mx = fmaxf(mx, __shfl_xor(mx, o));
  {
    unsigned long long g0 = __ballot(v0 == mx);
    unsigned long long g1 = __ballot(v1 == mx);
    int p0 = g0 ? 2 * (__ffsll(g0) - 1)     : (1 << 30);
    int p1 = g1 ? 2 * (__ffsll(g1) - 1) + 1 : (1 << 30);
    int pointer = min(p0, p1);

    // ---- masked tail: out[k]=0 for lp<k<S-1; out[S-1]=out[lp]=pointer ----
    for (int k = lp + 1 + lane; k <= S_ - 2; k += 64) out[b * S_ + k] = 0;
    if (lane == 0) {
      out[b * S_ + (S_ - 1)] = pointer;
      if (lp < S_ - 1) out[b * S_ + lp] = pointer;
    }

    // ---- chase k = lp-1 .. 0 ----
    int   ptr = pointer;
    float tg  = readlane_f((ptr & 1) ? L.y : L.x, ptr >> 1);  // ph[lp][ptr]
    const float* fb = feats + (size_t)b * S_ * T_;
    const float2 FL = *(const float2*)(fb + (size_t)lp * T_ + 2 * lane);
    float e = readlane_f((ptr & 1) ? FL.y : FL.x, ptr >> 1);  // feats[lp][ptr]

    float2 PA[CH_], FA[CH_], PB[CH_], FB[CH_];

    auto issue = [&](float2 (&P)[CH_], float2 (&F)[CH_], int k0) {
      #pragma unroll
      for (int s = 0; s < CH_; ++s) {
        int k = k0 - s; if (k < 0) k = 0;     // clamped slots never used
        P[s] = *(const float2*)(ph + ((size_t)k * B_ + b) * T_ + 2 * lane);
        F[s] = *(const float2*)(fb + (size_t)k * T_ + 2 * lane);
      }
    };
    auto process = [&](const float2 (&P)[CH_], const float2 (&F)[CH_], int k0) {
      #pragma unroll
      for (int s = 0; s < CH_; ++s) {
        const int k = k0 - s;
        if (k >= 0) {
          // candidates c_i = fl(fl(ph_k[i]+trans[i,ptr]) + e), i = 2l, 2l+1
          const float2 tr = *(const float2*)(transT + ptr * TS_ + 2 * lane);
          float cx = (P[s].x + tr.x) + e;
          float cy = (P[s].y + tr.y) + e;
          unsigned long long q0 = __ballot(cx == tg);
          unsigned long long q1 = __ballot(cy == tg);
          int a0 = q0 ? 2 * (__ffsll(q0) - 1)     : (1 << 30);
          int a1 = q1 ? 2 * (__ffsll(q1) - 1) + 1 : (1 << 30);
          ptr = min(a0, a1);
          if (lane == 0) out[b * S_ + k] = ptr;
          // next step (k-1) targets ph_k[ptr], feats[k][ptr]
          tg = readlane_f((ptr & 1) ? P[s].y : P[s].x, ptr >> 1);
          e  = readlane_f((ptr & 1) ? F[s].y : F[s].x, ptr >> 1);
        }
      }
    };

    issue(PA, FA, lp - 1);
    for (int k0 = lp - 1; k0 >= 0; k0 -= 2 * CH_) {
      issue(PB, FB, k0 - CH_);
      process(PA, FA, k0);
      issue(PA, FA, k0 - 2 * CH_);
      process(PB, FB, k0 - CH_);
    }
  }
}

extern "C" void kernel_launch(void* const* d_in, const int* in_sizes, int n_in,
                              void* d_out, int out_size, void* d_ws, size_t ws_size,
                              hipStream_t stream) {
  const float* feats = (const float*)d_in[0];   // (B,S,T) fp32
  const void*  mask  = d_in[1];                 // (B,S) bool-ish
  const float* trans = (const float*)d_in[2];   // (T,T) fp32
  float* ph = (float*)d_ws;                     // (S,B,T) fp32 = 64 MB
  int*   out = (int*)d_out;                     // (B,S) int32

  viterbi_forward<<<dim3(B_), dim3(256), 0, stream>>>(feats, trans, ph);
  viterbi_trace  <<<dim3(B_), dim3(64), 0, stream>>>(feats, mask, trans, ph, out);
}

// Round 7
// 414.724 us; speedup vs baseline: 1.4250x; 1.0978x over previous
//
#include <hip/hip_runtime.h>
#include <cstdint>
#include <cstddef>

constexpr int T_ = 128;
constexpr int S_ = 512;
constexpr int B_ = 256;
constexpr int START_ = T_ - 3;  // 125
constexpr int STOP_  = T_ - 2;  // 126

// Barrier that only drains LDS (lgkmcnt), NOT vmcnt: global ph-stores and
// e-prefetch loads legally stay in flight across it (thread-private data).
__device__ __forceinline__ void lds_barrier() {
  asm volatile("s_waitcnt lgkmcnt(0)\n\ts_barrier" ::: "memory");
}

// readlane: wave-uniform lane index (SGPR) -> ~VALU-speed broadcast.
__device__ __forceinline__ float readlane_f(float v, int sl) {
  return __int_as_float(__builtin_amdgcn_readlane(__float_as_int(v), sl));
}

// max-reduce over the 16 ig-lanes (lane bits [0,4)) in pure row-DPP:
// quad xor1 (0xB1), quad xor2 (0x4E), row_half_mirror (0x141: l^7 == l^4
// once quad-uniform), row_mirror (0x140: l^15 == l^8 once 8-uniform).
__device__ __forceinline__ float ig16_rmax(float m) {
  int x = __builtin_amdgcn_mov_dpp(__float_as_int(m), 0xB1, 0xF, 0xF, true);
  m = fmaxf(m, __int_as_float(x));
  x = __builtin_amdgcn_mov_dpp(__float_as_int(m), 0x4E, 0xF, 0xF, true);
  m = fmaxf(m, __int_as_float(x));
  x = __builtin_amdgcn_mov_dpp(__float_as_int(m), 0x141, 0xF, 0xF, true);
  m = fmaxf(m, __int_as_float(x));
  x = __builtin_amdgcn_mov_dpp(__float_as_int(m), 0x140, 0xF, 0xF, true);
  m = fmaxf(m, __int_as_float(x));
  return m;
}

// ---------------------------------------------------------------------------
// Forward: value-only Viterbi recursion, stores part_hist (S,B,T) fp32.
// KEY CHANGE vs R4/R6: 512 threads (8 waves = 2 waves/SIMD). R1-R6 all ran
// 4 waves/CU = 1 wave/SIMD, so the per-step serial skeleton (barrier ->
// ds_read pipe+latency -> VALU -> DPP -> write -> barrier) was fully
// exposed (~1400 cyc/step, VALUBusy 43%). With 2 waves/SIMD one wave's
// VALU covers the other's waits. Thread (ig,jg) covers i in [8ig,8ig+8) x
// j in [4jg,4jg+4); cross-ig reduce = 4 row-DPP stages; e-prefetch 4-8
// steps deep in named A/B register groups.
// Bit-exact vs reference: max exactly associative, fl monotone =>
// max_i fl(fl(p+tr)+e) == fl(max_i fl(p+tr) + e).
// ---------------------------------------------------------------------------
__global__ __launch_bounds__(512, 2) void viterbi_forward(
    const float* __restrict__ feats,   // (B,S,T)
    const float* __restrict__ trans,   // (T,T)
    float* __restrict__ ph)            // (S,B,T) workspace
{
  const int b    = blockIdx.x;
  const int tid  = threadIdx.x;
  const int lane = tid & 63;
  const int ig   = lane & 15;          // i-chunk: i in [8ig, 8ig+8)
  const int jg   = tid >> 4;           // 0..31
  const int j0   = jg * 4;

  // padded part: value i at float offset i + 4*(i>>3); 192 floats/buffer.
  // Thread reads granules 3ig, 3ig+1: ig and ig+8 alias -> 2-way (free).
  __shared__ alignas(16) float part[2][192];

  // trans tile: tc[ii] = trans[8ig+ii][j0..j0+3] (32 VGPRs, fixed over t)
  float4 tc[8];
  #pragma unroll
  for (int ii = 0; ii < 8; ++ii)
    tc[ii] = *(const float4*)&trans[(8 * ig + ii) * T_ + j0];

  const float* fb = feats + (size_t)b * S_ * T_;
  const int woff  = j0 + 4 * (j0 >> 3);

  // t = 0: part0 = emit[0] + trans[START,:]
  float4 e0 = *(const float4*)&fb[j0];
  float4 ts = *(const float4*)&trans[START_ * T_ + j0];
  float4 p0 = make_float4(e0.x + ts.x, e0.y + ts.y, e0.z + ts.z, e0.w + ts.w);
  if (ig == 0) {
    *(float4*)&part[0][woff] = p0;
    *(float4*)&ph[(size_t)b * T_ + j0] = p0;
  }
  __syncthreads();

  auto stepf = [&](int t, float4 e4) {
    const float4* p4 = (const float4*)part[(t - 1) & 1];
    float4 pa = p4[3 * ig];
    float4 pb = p4[3 * ig + 1];
    const float pv[8] = {pa.x, pa.y, pa.z, pa.w, pb.x, pb.y, pb.z, pb.w};
    float m[4];
    #pragma unroll
    for (int c = 0; c < 4; ++c) {
      float a0 = pv[0] + ((const float*)&tc[0])[c];
      float a1 = pv[1] + ((const float*)&tc[1])[c];
      float a2 = pv[2] + ((const float*)&tc[2])[c];
      float a3 = pv[3] + ((const float*)&tc[3])[c];
      float a4 = pv[4] + ((const float*)&tc[4])[c];
      float a5 = pv[5] + ((const float*)&tc[5])[c];
      float a6 = pv[6] + ((const float*)&tc[6])[c];
      float a7 = pv[7] + ((const float*)&tc[7])[c];
      float mm = fmaxf(fmaxf(fmaxf(a0, a1), fmaxf(a2, a3)),
                       fmaxf(fmaxf(a4, a5), fmaxf(a6, a7)));
      m[c] = ig16_rmax(mm);
    }
    float4 np4 = make_float4(m[0] + e4.x, m[1] + e4.y, m[2] + e4.z, m[3] + e4.w);
    if (ig == 0) *(float4*)&part[t & 1][woff] = np4;
    lds_barrier();
    if (ig == 0)
      *(float4*)&ph[((size_t)t * B_ + b) * T_ + j0] = np4;  // off critical path
  };

  // emission prefetch: 8 rows in flight (named A/B groups of 4, no rotation)
  float4 EA[4], EB[4];
  #pragma unroll
  for (int u = 0; u < 4; ++u)
    EA[u] = *(const float4*)&fb[(size_t)(1 + u) * T_ + j0];

  for (int t0 = 1; t0 < S_; t0 += 8) {
    #pragma unroll
    for (int u = 0; u < 4; ++u) {
      int tr = t0 + 4 + u; if (tr > S_ - 1) tr = S_ - 1;
      EB[u] = *(const float4*)&fb[(size_t)tr * T_ + j0];
    }
    #pragma unroll
    for (int u = 0; u < 4; ++u) { int t = t0 + u; if (t < S_) stepf(t, EA[u]); }
    #pragma unroll
    for (int u = 0; u < 4; ++u) {
      int tr = t0 + 8 + u; if (tr > S_ - 1) tr = S_ - 1;
      EA[u] = *(const float4*)&fb[(size_t)tr * T_ + j0];
    }
    #pragma unroll
    for (int u = 0; u < 4; ++u) { int t = t0 + 4 + u; if (t < S_) stepf(t, EB[u]); }
  }
}

// ---------------------------------------------------------------------------
// Trace: one wave (64 lanes) per b, grid 256. UNCHANGED from R4/R6 (isolate
// the forward experiment). bp recomputed on-path only via equality-ballot;
// bit-exact first-occurrence argmax vs reference.
// ---------------------------------------------------------------------------
constexpr int CH_ = 8;   // chunk size (steps per buffer)
constexpr int TS_ = 130; // transT row stride (even: float2-aligned, 2-way ok)

__global__ __launch_bounds__(64, 1) void viterbi_trace(
    const float* __restrict__ feats,   // (B,S,T)
    const void*  __restrict__ mask,    // (B,S) dtype detected at runtime
    const float* __restrict__ trans,   // (T,T)
    const float* __restrict__ ph,      // (S,B,T)
    int* __restrict__ out)             // (B,S) int32
{
  const int b    = blockIdx.x;
  const int lane = threadIdx.x;

  __shared__ alignas(16) float transT[T_ * TS_];  // transT[j*TS+i] = trans[i][j]
  #pragma unroll 4
  for (int g = lane; g < T_ * T_; g += 64) {
    int i = g >> 7, jj = g & (T_ - 1);
    transT[jj * TS_ + i] = trans[g];
  }
  __syncthreads();

  // ---- sequence length (mask dtype: uint8 / float32 / int32) ----
  int len = 0;
  {
    const int w0 = *(const int*)mask;  // element (0,0) is always true
    if (w0 == 0x01010101) {
      const unsigned char* m = (const unsigned char*)mask + (size_t)b * S_;
      for (int s = lane; s < S_; s += 64) len += (m[s] != 0);
    } else if (w0 == 0x3F800000) {
      const float* m = (const float*)mask + (size_t)b * S_;
      for (int s = lane; s < S_; s += 64) len += (m[s] != 0.0f);
    } else {
      const int* m = (const int*)mask + (size_t)b * S_;
      for (int s = lane; s < S_; s += 64) len += (m[s] != 0);
    }
    #pragma unroll
    for (int o = 32; o > 0; o >>= 1) len += __shfl_xor(len, o);
  }
  const int lp = len - 1;              // last valid position (>= S/2-1)

  // ---- final pointer: first argmax_i(ph_lp[i] + trans[i][STOP]) ----
  const float2 L = *(const float2*)(ph + ((size_t)lp * B_ + b) * T_ + 2 * lane);
  float v0 = L.x + transT[STOP_ * TS_ + 2 * lane];
  float v1 = L.y + transT[STOP_ * TS_ + 2 * lane + 1];
  float mx = fmaxf(v0, v1);
  #pragma unroll
  for (int o = 32; o > 0; o >>= 1) mx = fmaxf(mx, __shfl_xor(mx, o));
  {
    unsigned long long g0 = __ballot(v0 == mx);
    unsigned long long g1 = __ballot(v1 == mx);
    int p0 = g0 ? 2 * (__ffsll(g0) - 1)     : (1 << 30);
    int p1 = g1 ? 2 * (__ffsll(g1) - 1) + 1 : (1 << 30);
    int pointer = min(p0, p1);

    // ---- masked tail: out[k]=0 for lp<k<S-1; out[S-1]=out[lp]=pointer ----
    for (int k = lp + 1 + lane; k <= S_ - 2; k += 64) out[b * S_ + k] = 0;
    if (lane == 0) {
      out[b * S_ + (S_ - 1)] = pointer;
      if (lp < S_ - 1) out[b * S_ + lp] = pointer;
    }

    // ---- chase k = lp-1 .. 0 ----
    int   ptr = pointer;
    float tg  = readlane_f((ptr & 1) ? L.y : L.x, ptr >> 1);  // ph[lp][ptr]
    const float* fb = feats + (size_t)b * S_ * T_;
    const float2 FL = *(const float2*)(fb + (size_t)lp * T_ + 2 * lane);
    float e = readlane_f((ptr & 1) ? FL.y : FL.x, ptr >> 1);  // feats[lp][ptr]

    float2 PA[CH_], FA[CH_], PB[CH_], FB[CH_];

    auto issue = [&](float2 (&P)[CH_], float2 (&F)[CH_], int k0) {
      #pragma unroll
      for (int s = 0; s < CH_; ++s) {
        int k = k0 - s; if (k < 0) k = 0;     // clamped slots never used
        P[s] = *(const float2*)(ph + ((size_t)k * B_ + b) * T_ + 2 * lane);
        F[s] = *(const float2*)(fb + (size_t)k * T_ + 2 * lane);
      }
    };
    auto process = [&](const float2 (&P)[CH_], const float2 (&F)[CH_], int k0) {
      #pragma unroll
      for (int s = 0; s < CH_; ++s) {
        const int k = k0 - s;
        if (k >= 0) {
          // candidates c_i = fl(fl(ph_k[i]+trans[i,ptr]) + e), i = 2l, 2l+1
          const float2 tr = *(const float2*)(transT + ptr * TS_ + 2 * lane);
          float cx = (P[s].x + tr.x) + e;
          float cy = (P[s].y + tr.y) + e;
          unsigned long long q0 = __ballot(cx == tg);
          unsigned long long q1 = __ballot(cy == tg);
          int a0 = q0 ? 2 * (__ffsll(q0) - 1)     : (1 << 30);
          int a1 = q1 ? 2 * (__ffsll(q1) - 1) + 1 : (1 << 30);
          ptr = min(a0, a1);
          if (lane == 0) out[b * S_ + k] = ptr;
          // next step (k-1) targets ph_k[ptr], feats[k][ptr]
          tg = readlane_f((ptr & 1) ? P[s].y : P[s].x, ptr >> 1);
          e  = readlane_f((ptr & 1) ? F[s].y : F[s].x, ptr >> 1);
        }
      }
    };

    issue(PA, FA, lp - 1);
    for (int k0 = lp - 1; k0 >= 0; k0 -= 2 * CH_) {
      issue(PB, FB, k0 - CH_);
      process(PA, FA, k0);
      issue(PA, FA, k0 - 2 * CH_);
      process(PB, FB, k0 - CH_);
    }
  }
}

extern "C" void kernel_launch(void* const* d_in, const int* in_sizes, int n_in,
                              void* d_out, int out_size, void* d_ws, size_t ws_size,
                              hipStream_t stream) {
  const float* feats = (const float*)d_in[0];   // (B,S,T) fp32
  const void*  mask  = d_in[1];                 // (B,S) bool-ish
  const float* trans = (const float*)d_in[2];   // (T,T) fp32
  float* ph = (float*)d_ws;                     // (S,B,T) fp32 = 64 MB
  int*   out = (int*)d_out;                     // (B,S) int32

  viterbi_forward<<<dim3(B_), dim3(512), 0, stream>>>(feats, trans, ph);
  viterbi_trace  <<<dim3(B_), dim3(64), 0, stream>>>(feats, mask, trans, ph, out);
}